// Round 7
// baseline (1405.178 us; speedup 1.0000x reference)
//
#include <hip/hip_runtime.h>
#include <math.h>

#define N_MEM 100
#define C_DIM 768
#define HW_SZ 2304            // 48*48
#define TEMP 0.07f
#define EPS_F 1e-8f
#define LAM_F 0.01f           // 1/N_MEM
#define NORM_EPS 1e-12f

#define NS   4                // n-split stripes in mTp layout (fixed)
#define SW   25               // stripe width (N_MEM/NS)
#define SWP  28               // padded stripe (16B-aligned for s_load_dwordx4)
#define ROWS 64               // rows per block
#define SCP  101              // LDS row pad: 101 % 32 = 5, coprime -> 2-way max
#define CB   24               // recon c-tile per register block
#define ZB   8                // scores c-loop batch: 8 z-loads in flight
#define NW_R 8                // recon waves per block (c-split depth)  [R7 change]

// -------------------------------------------------------------------------
// Kernel 1: L2-normalize memory rows, store PADDED-TRANSPOSED:
// mTp[c][ns][SWP]. Same value bits as R1's mT (same reduction).
// -------------------------------------------------------------------------
__global__ __launch_bounds__(64) void prep_mT(const float* __restrict__ mem,
                                              float* __restrict__ mTp) {
#pragma clang fp contract(off)
    const int n = blockIdx.x;        // 0..99
    const int lane = threadIdx.x;    // 0..63
    const float* row = mem + n * C_DIM;

    float ss = 0.f;
    for (int c = lane; c < C_DIM; c += 64) {
        float v = row[c];
        ss = fmaf(v, v, ss);
    }
    for (int off = 32; off > 0; off >>= 1)
        ss += __shfl_down(ss, off);
    float norm = sqrtf(__shfl(ss, 0));
    float inv = 1.0f / fmaxf(norm, NORM_EPS);

    const int nsI = n / SW, j = n % SW;
    for (int c = lane; c < C_DIM; c += 64)
        mTp[(size_t)c * (NS * SWP) + nsI * SWP + j] = row[c] * inv;
}

// -------------------------------------------------------------------------
// Kernel 2: scores + softmax + shrinkage + renorm -> writes w_hat (What).
// UNCHANGED from R6 (bit-stable: absmax 4.94e-3 vs threshold 5.27e-3).
// -------------------------------------------------------------------------
__global__ __launch_bounds__(256) void memmod_scores(const float* __restrict__ F,
                                                     const float* __restrict__ mTp,
                                                     float* __restrict__ What) {
#pragma clang fp contract(off)
    __shared__ float sc[ROWS][SCP];

    const int tid  = threadIdx.x;
    const int lane = tid & 63;
    const int ws   = tid >> 6;
    const int wsu  = __builtin_amdgcn_readfirstlane(ws);   // force SGPR addr
    const int blk  = blockIdx.x;                 // 0..2303
    const int b    = blk / 36;                   // 36 blocks per image
    const int hw   = (blk % 36) * 64 + lane;     // 0..2303
    const int rowg = b * HW_SZ + hw;             // global row id
    const size_t plane = (size_t)b * C_DIM * HW_SZ + hw;

    float acc[SW];
#pragma unroll
    for (int j = 0; j < SW; ++j) acc[j] = 0.f;
    float ss = 0.f;

    // ---- scores: batched loads, sequential-c FMA chains ----
    const float* Fp = F + plane;
    for (int c0 = 0; c0 < C_DIM; c0 += ZB) {
        float zb[ZB];                            // static indices -> VGPRs
#pragma unroll
        for (int u = 0; u < ZB; ++u)
            zb[u] = Fp[(size_t)(c0 + u) * HW_SZ];    // 8 coalesced loads in flight
#pragma unroll
        for (int u = 0; u < ZB; ++u) {
            const float zc = zb[u];
            ss = fmaf(zc, zc, ss);
            const float* mch = mTp + (size_t)(c0 + u) * (NS * SWP) + wsu * SWP;
#pragma unroll
            for (int j = 0; j < SW; ++j)
                acc[j] = fmaf(zc, mch[j], acc[j]);
        }
    }

    // ---- stage scores to LDS (read-only afterwards -> race-free) ----
#pragma unroll
    for (int j = 0; j < SW; ++j)
        sc[lane][wsu * SW + j] = acc[j];
    __syncthreads();

    // ---- softmax + shrinkage: R1's exact op sequence, n = 0..99 ----
    const float scale = 1.0f / (fmaxf(sqrtf(ss), NORM_EPS) * TEMP);
    float mx = -INFINITY;
    for (int n = 0; n < N_MEM; ++n)
        mx = fmaxf(mx, sc[lane][n] * scale);
    float sum = 0.f;
    for (int n = 0; n < N_MEM; ++n)
        sum += expf(sc[lane][n] * scale - mx);
    float s2 = 0.f;
    for (int n = 0; n < N_MEM; ++n) {
        const float e = expf(sc[lane][n] * scale - mx);   // same bits as pass 2
        const float w = e / sum;
        const float d = w - LAM_F;
        s2 += (d > 0.f ? d : 0.f) * w / (fabsf(d) + EPS_F);
    }
    const float s2c = fmaxf(s2, EPS_F);

    // ---- own stripe: recompute wh from registers (same bits), emit ----
    float* wout = What + (size_t)rowg * N_MEM + wsu * SW;
#pragma unroll
    for (int j = 0; j < SW; ++j) {
        const float e = expf(acc[j] * scale - mx);
        const float w = e / sum;
        const float d = w - LAM_F;
        const float wh = (d > 0.f ? d : 0.f) * w / (fabsf(d) + EPS_F);
        wout[j] = wh / s2c;
    }
}

// -------------------------------------------------------------------------
// Kernel 3: reconstruction  Fhat[b][c][hw] = sum_n w_hat[row][n]*m[n][c].
// R7 change: 512-thread blocks (8 waves), c-split deepened 4 -> 8: wave ws
// owns a 96-wide c-stripe of the same 64 rows. 18432 waves (4.5/SIMD),
// 4 blocks x 8 waves = 32 waves/CU fits LDS (4x26KB) and VGPR (64).
// Per-output n-order (nc 0..3, j 0..24 ascending) unchanged -> recon
// bit-identical to R5/R6.
// -------------------------------------------------------------------------
__global__ __launch_bounds__(512) void memmod_recon(const float* __restrict__ What,
                                                    const float* __restrict__ mTp,
                                                    float* __restrict__ Fhat) {
#pragma clang fp contract(off)
    __shared__ float wh[ROWS][SCP];

    const int tid  = threadIdx.x;                // 0..511
    const int lane = tid & 63;
    const int ws   = tid >> 6;                   // 0..7
    const int wsu  = __builtin_amdgcn_readfirstlane(ws);
    const int blk  = blockIdx.x;
    const int b    = blk / 36;
    const int h0   = (blk % 36) * 64;
    const int hw   = h0 + lane;

    // ---- stage 64 rows x 100 w_hat into LDS (coalesced float4 reads) ----
    const float4* src4 =
        reinterpret_cast<const float4*>(What + ((size_t)b * HW_SZ + h0) * N_MEM);
    for (int i = tid; i < ROWS * N_MEM / 4; i += 512) {
        const float4 v = src4[i];
        const int f = i * 4, r = f / N_MEM, n = f % N_MEM;
        wh[r][n] = v.x; wh[r][n + 1] = v.y; wh[r][n + 2] = v.z; wh[r][n + 3] = v.w;
    }
    __syncthreads();

    const size_t plane = (size_t)b * C_DIM * HW_SZ + hw;
    float* Fo = Fhat + plane;
    const int c0w = wsu * (C_DIM / NW_R);        // 96-wide c-stripe

    for (int cb = 0; cb < C_DIM / NW_R; cb += CB) {
        float v[CB];
#pragma unroll
        for (int t = 0; t < CB; ++t) v[t] = 0.f;

#pragma unroll
        for (int nc = 0; nc < NS; ++nc) {
            float wr[SW];
#pragma unroll
            for (int j = 0; j < SW; ++j)
                wr[j] = wh[lane][nc * SW + j];    // stride 101 -> 2-way max
#pragma unroll
            for (int t = 0; t < CB; ++t) {
                const float* mch =
                    mTp + (size_t)(c0w + cb + t) * (NS * SWP) + nc * SWP; // s_load
#pragma unroll
                for (int j = 0; j < SW; ++j)
                    v[t] = fmaf(wr[j], mch[j], v[t]);   // n ascending overall
            }
        }
#pragma unroll
        for (int t = 0; t < CB; ++t)
            Fo[(size_t)(c0w + cb + t) * HW_SZ] = v[t];  // coalesced per c
    }
}

// -------------------------------------------------------------------------
extern "C" void kernel_launch(void* const* d_in, const int* in_sizes, int n_in,
                              void* d_out, int out_size, void* d_ws, size_t ws_size,
                              hipStream_t stream) {
    const float* F   = (const float*)d_in[0];   // [64,768,48,48]
    const float* mem = (const float*)d_in[1];   // [100,768]
    float* Fhat = (float*)d_out;                               // 113,246,208 floats
    float* What = (float*)d_out + (size_t)64 * 768 * 48 * 48;  // 14,745,600 floats
    float* mTp  = (float*)d_ws;                                // 768*4*28 floats

    prep_mT<<<N_MEM, 64, 0, stream>>>(mem, mTp);
    memmod_scores<<<2304, 256, 0, stream>>>(F, mTp, What);
    memmod_recon<<<2304, 512, 0, stream>>>(What, mTp, Fhat);
}